// Round 4
// baseline (280.461 us; speedup 1.0000x reference)
//
#include <hip/hip_runtime.h>

// Shapes (fixed by setup_inputs): N=1, L1=256, K=128, L2=1024,
// c_s=384, c_m=256, ch=32, c_z=128
#define L1V 256
#define L2V 1024
#define KV  128
#define CSV 384
#define CMV 256
#define CHV 32
#define CZV 128

__device__ __forceinline__ float4 f4zero() { return make_float4(0.f,0.f,0.f,0.f); }

// Per-row LN stats (full-wave reduction over 256 elems = 64 lanes x float4),
// then accumulate normalized row into xs.
__device__ __forceinline__ void ln_accum(const float4 x, float4& xs) {
  float s1 = x.x + x.y + x.z + x.w;
  float s2 = fmaf(x.x, x.x, fmaf(x.y, x.y, fmaf(x.z, x.z, x.w * x.w)));
  #pragma unroll
  for (int off = 32; off > 0; off >>= 1) {
    s1 += __shfl_xor(s1, off, 64);
    s2 += __shfl_xor(s2, off, 64);
  }
  const float mu   = s1 * (1.0f / CMV);
  const float rstd = rsqrtf(s2 * (1.0f / CMV) - mu * mu + 1e-5f);
  xs.x = fmaf(x.x - mu, rstd, xs.x);
  xs.y = fmaf(x.y - mu, rstd, xs.y);
  xs.z = fmaf(x.z - mu, rstd, xs.z);
  xs.w = fmaf(x.w - mu, rstd, xs.w);
}

// ---------------------------------------------------------------------------
// FUSED kernel 1: blocks [0,1024) compute msum (one block per j);
// blocks [1024,1280) compute T (16 idx-chunks x 16 i-chunks), recomputing
// their 16 `a` rows in-block (LN(s)@W_ab, ~0.4 MFLOP redundant — trivial).
// Fusion co-schedules the L2-latency-bound t work under HBM-bound msum waves
// and removes two dispatches + launch gaps.
// ---------------------------------------------------------------------------
__global__ __launch_bounds__(256) void fused1_kernel(
    const float* __restrict__ m, const float* __restrict__ g_ag,
    const float* __restrict__ b_ag, const float* __restrict__ Wag,
    const float* __restrict__ bag,
    const float* __restrict__ s, const float* __restrict__ g_ab,
    const float* __restrict__ b_ab, const float* __restrict__ Wab,
    const float* __restrict__ bab,
    const float* __restrict__ Wout,
    float* __restrict__ msum, float* __restrict__ T)
{
  __shared__ float smem[16 * CSV + 16 * CHV];  // 26.6 KB, unioned across paths
  const int tid = threadIdx.x;

  if (blockIdx.x < 1024) {
    // ---------------- msum path: m_sum[j,c] = sum_k LN-row_k @ W_ag (+bias)
    const int j    = blockIdx.x;
    const int wave = tid >> 6;
    const int lane = tid & 63;

    const float4* base = (const float4*)m;  // row k at float4 idx (k*1024+j)*64

    float4 xs = f4zero();
    float4 x0 = base[(((size_t)wave << 10) + j) * 64 + lane];
    float4 x1 = base[(((size_t)(wave + 4) << 10) + j) * 64 + lane];

    for (int k = wave; k < KV; k += 8) {
      float4 n0 = f4zero(), n1 = f4zero();
      if (k + 8  < KV) n0 = base[(((size_t)(k + 8)  << 10) + j) * 64 + lane];
      if (k + 12 < KV) n1 = base[(((size_t)(k + 12) << 10) + j) * 64 + lane];
      ln_accum(x0, xs);
      ln_accum(x1, xs);
      x0 = n0; x1 = n1;
    }

    float* xsum = smem;             // [4][256]
    float* y    = smem + 1024;      // [256]
    float* pr   = smem + 1280;      // [256]

    ((float4*)(xsum + wave * CMV))[lane] = xs;
    __syncthreads();

    y[tid] = (xsum[tid] + xsum[CMV + tid] + xsum[2 * CMV + tid] + xsum[3 * CMV + tid])
             * g_ag[tid] + (float)KV * b_ag[tid];
    __syncthreads();

    const int c     = tid & 31;
    const int chunk = tid >> 5;
    float p = 0.f;
    #pragma unroll
    for (int q = 0; q < 32; ++q) {
      const int e = (chunk << 5) + q;
      p = fmaf(y[e], Wag[(e << 5) + c], p);
    }
    pr[tid] = p;
    __syncthreads();
    if (tid < 32) {
      float acc = 0.f;
      #pragma unroll
      for (int r = 0; r < 8; ++r) acc += pr[tid + (r << 5)];
      msum[(j << 5) + tid] = acc + (float)KV * bag[tid];
    }
  } else {
    // ---------------- T path: T[i,idx] = a[i,:] @ Wout[:,idx], idx=e*128+z
    const int bb    = blockIdx.x - 1024;   // 0..255
    const int chunk = bb & 15;             // idx chunk
    const int i0    = (bb >> 4) << 4;      // i-chunk * 16
    const int idx   = (chunk << 8) + tid;  // 0..4095

    float* ys = smem;               // [16][384]
    float* as = smem + 16 * CSV;    // [16][32]

    // Stage A: LN of 16 s-rows. 16 lanes per row; lane sub reads float4s
    // q*16+sub (coalesced 256B per q within the group).
    {
      const int r   = tid >> 4;     // 0..15
      const int sub = tid & 15;
      const float4* srow = (const float4*)(s + (size_t)(i0 + r) * CSV);
      float4 v[6];
      #pragma unroll
      for (int q = 0; q < 6; ++q) v[q] = srow[(q << 4) + sub];

      float s1 = 0.f, s2 = 0.f;
      #pragma unroll
      for (int q = 0; q < 6; ++q) {
        s1 += v[q].x + v[q].y + v[q].z + v[q].w;
        s2 += fmaf(v[q].x, v[q].x, fmaf(v[q].y, v[q].y,
              fmaf(v[q].z, v[q].z, v[q].w * v[q].w)));
      }
      #pragma unroll
      for (int off = 8; off > 0; off >>= 1) {   // reduce within 16-lane group
        s1 += __shfl_xor(s1, off, 64);
        s2 += __shfl_xor(s2, off, 64);
      }
      const float mu   = s1 * (1.0f / CSV);
      const float rstd = rsqrtf(s2 * (1.0f / CSV) - mu * mu + 1e-5f);

      #pragma unroll
      for (int q = 0; q < 6; ++q) {
        const float4 gg = ((const float4*)g_ab)[(q << 4) + sub];
        const float4 bbv = ((const float4*)b_ab)[(q << 4) + sub];
        float4 yv;
        yv.x = (v[q].x - mu) * rstd * gg.x + bbv.x;
        yv.y = (v[q].y - mu) * rstd * gg.y + bbv.y;
        yv.z = (v[q].z - mu) * rstd * gg.z + bbv.z;
        yv.w = (v[q].w - mu) * rstd * gg.w + bbv.w;
        ((float4*)(ys + r * CSV))[(q << 4) + sub] = yv;
      }
    }
    __syncthreads();

    // Stage B: a[r,c] = ys[r,:] @ Wab[:,c] + bab[c]; thread does rows r0,r0+8
    {
      const int c  = tid & 31;
      const int r0 = tid >> 5;   // 0..7
      float acc0 = 0.f, acc1 = 0.f;
      for (int e = 0; e < CSV; ++e) {
        const float w = Wab[(e << 5) + c];
        acc0 = fmaf(ys[r0 * CSV + e], w, acc0);
        acc1 = fmaf(ys[(r0 + 8) * CSV + e], w, acc1);
      }
      const float bc = bab[c];
      as[(r0 << 5) + c]       = acc0 + bc;
      as[((r0 + 8) << 5) + c] = acc1 + bc;
    }
    __syncthreads();

    // Stage C: Wout column in 32 VGPRs, 16 i-outputs per thread.
    float w[32];
    #pragma unroll
    for (int c = 0; c < 32; ++c) w[c] = Wout[(c << 12) + idx];

    #pragma unroll 4
    for (int ii = 0; ii < 16; ++ii) {
      float acc = 0.f;
      #pragma unroll
      for (int c = 0; c < 32; ++c)
        acc = fmaf(as[(ii << 5) + c], w[c], acc);
      T[((size_t)(i0 + ii) << 12) + idx] = acc;
    }
  }
}

// ---------------------------------------------------------------------------
// Kernel C: out[i,j,z] = (m_sum[j,:] @ T[i][:,z] + b_out[z]) / (K + 1e-3)
// grid = (2 j-halves, 256 i) = 512 blocks (2/CU); T_i loaded ONCE into 128
// VGPRs (8 MB total T traffic); msum staged through an 8 KB LDS tile with a
// REGISTER double-buffer (R3): tile t+1 fetched into VGPRs while computing
// tile t, hiding global latency behind the 8 barrier pairs.
// ---------------------------------------------------------------------------
__global__ __launch_bounds__(256) void out_kernel(
    const float* __restrict__ msum, const float* __restrict__ T,
    const float* __restrict__ bout, float* __restrict__ out)
{
  const int half = blockIdx.x;   // 0..1
  const int i    = blockIdx.y;   // 0..255
  const int tid  = threadIdx.x;
  const int zq   = (tid & 31) << 2;  // z quad start: 0,4,...,124
  const int jg   = tid >> 5;         // 0..7

  float4 Treg[32];
  #pragma unroll
  for (int e = 0; e < 32; ++e)
    Treg[e] = *(const float4*)(T + ((size_t)i << 12) + (e << 7) + zq);

  const float4 bz = *(const float4*)(bout + zq);
  const float inv_norm = 1.0f / ((float)KV + 1e-3f);

  const float4* msrc = (const float4*)msum + ((size_t)half << 12);  // half*512 rows * 8 f4
  float4 p0 = msrc[tid];
  float4 p1 = msrc[tid + 256];

  __shared__ float ms[64 * CHV];  // 8 KB

  for (int tile = 0; tile < 8; ++tile) {
    __syncthreads();  // previous tile's reads done before overwrite
    ((float4*)ms)[tid]       = p0;
    ((float4*)ms)[tid + 256] = p1;
    __syncthreads();
    if (tile < 7) {   // prefetch next tile while computing this one
      p0 = msrc[((tile + 1) << 9) + tid];
      p1 = msrc[((tile + 1) << 9) + tid + 256];
    }

    const int j0 = (half << 9) + (tile << 6);
    #pragma unroll
    for (int jj = 0; jj < 8; ++jj) {
      const int j = jg + (jj << 3);            // 0..63 within tile
      const float4* mr = (const float4*)(ms + (j << 5));
      float4 acc = f4zero();
      #pragma unroll
      for (int eq = 0; eq < 8; ++eq) {
        const float4 m4 = mr[eq];
        const float4 t0 = Treg[(eq << 2) + 0];
        const float4 t1 = Treg[(eq << 2) + 1];
        const float4 t2 = Treg[(eq << 2) + 2];
        const float4 t3 = Treg[(eq << 2) + 3];
        acc.x = fmaf(m4.x, t0.x, fmaf(m4.y, t1.x, fmaf(m4.z, t2.x, fmaf(m4.w, t3.x, acc.x))));
        acc.y = fmaf(m4.x, t0.y, fmaf(m4.y, t1.y, fmaf(m4.z, t2.y, fmaf(m4.w, t3.y, acc.y))));
        acc.z = fmaf(m4.x, t0.z, fmaf(m4.y, t1.z, fmaf(m4.z, t2.z, fmaf(m4.w, t3.z, acc.z))));
        acc.w = fmaf(m4.x, t0.w, fmaf(m4.y, t1.w, fmaf(m4.z, t2.w, fmaf(m4.w, t3.w, acc.w))));
      }
      float4 o;
      o.x = (acc.x + bz.x) * inv_norm;
      o.y = (acc.y + bz.y) * inv_norm;
      o.z = (acc.z + bz.z) * inv_norm;
      o.w = (acc.w + bz.w) * inv_norm;
      *(float4*)(out + ((size_t)i << 17) + ((size_t)(j0 + j) << 7) + zq) = o;
    }
  }
}

// ---------------------------------------------------------------------------
extern "C" void kernel_launch(void* const* d_in, const int* in_sizes, int n_in,
                              void* d_out, int out_size, void* d_ws, size_t ws_size,
                              hipStream_t stream) {
  (void)in_sizes; (void)n_in; (void)out_size; (void)ws_size;
  const float* s    = (const float*)d_in[0];
  const float* m    = (const float*)d_in[1];
  const float* g_ab = (const float*)d_in[2];
  const float* b_ab = (const float*)d_in[3];
  const float* g_ag = (const float*)d_in[4];
  const float* b_ag = (const float*)d_in[5];
  const float* Wab  = (const float*)d_in[6];
  const float* bab  = (const float*)d_in[7];
  const float* Wag  = (const float*)d_in[8];
  const float* bag  = (const float*)d_in[9];
  const float* Wout = (const float*)d_in[10];
  const float* bout = (const float*)d_in[11];
  float* out = (float*)d_out;

  // workspace layout (fp32): msum[1024*32] | T[256*32*128]
  float* msum = (float*)d_ws;
  float* T    = msum + 32768;   // 4 MB

  hipLaunchKernelGGL(fused1_kernel, dim3(1280), dim3(256), 0, stream,
                     m, g_ag, b_ag, Wag, bag,
                     s, g_ab, b_ab, Wab, bab,
                     Wout, msum, T);
  hipLaunchKernelGGL(out_kernel, dim3(2, 256), dim3(256), 0, stream,
                     msum, T, bout, out);
}